// Round 3
// baseline (519.859 us; speedup 1.0000x reference)
//
#include <hip/hip_runtime.h>
#include <hip/hip_cooperative_groups.h>
#include <math.h>

namespace cg = cooperative_groups;

#define EPS 1e-6f

// Native clang vector type — required by __builtin_nontemporal_{load,store}
typedef float __attribute__((ext_vector_type(4))) fx4;

// Single cooperative kernel. 512 blocks x 256 threads = 2 blocks/CU
// co-resident (16 KB LDS, <=128 VGPR via launch_bounds), 16 planes/block.
//   phase 1: per-plane spatial mean (wave-per-plane, shuffle reduce)
//   grid.sync()
//   phase 2: qk conv1d + elu + depthwise 3x3 + s_new/out/z_new
__global__ __launch_bounds__(256, 2) void mega_kernel(
    const float* __restrict__ x, const float* __restrict__ s,
    const float* __restrict__ z, const float* __restrict__ wq,
    const float* __restrict__ wk, const float* __restrict__ wv,
    float* __restrict__ y, float* __restrict__ out,
    float* __restrict__ s_new, float* __restrict__ z_new) {
    __shared__ float tile[4096];

    int t = threadIdx.x;
    int wave = t >> 6;           // 0..3
    int lane = t & 63;
    int pbase = blockIdx.x << 4; // 16 planes per block

    // ---- phase 1: spatial means; each wave owns 4 planes, no block syncs ----
#pragma unroll
    for (int i = 0; i < 4; ++i) {
        int plane = pbase + (wave << 2) + i;
        const fx4* xp = (const fx4*)(x + (size_t)plane * 4096);
        float sum = 0.f;
#pragma unroll 8
        for (int k = 0; k < 16; ++k) {   // 1024 fx4 / 64 lanes = 16 each
            fx4 v = xp[lane + k * 64];
            sum += v.x + v.y + v.z + v.w;
        }
#pragma unroll
        for (int off = 32; off > 0; off >>= 1)
            sum += __shfl_down(sum, off, 64);
        if (lane == 0) y[plane] = sum * (1.0f / 4096.0f);
    }

    cg::this_grid().sync();

    // ---- phase 2: fused qk + depthwise conv + outputs ----
    int ty = t >> 4;             // 0..15
    int tx = t & 15;             // 0..15
    int col0 = tx << 2;          // 0,4,...,60
    float lm = (col0 == 0) ? 0.f : 1.f;
    float rm = (col0 == 60) ? 0.f : 1.f;
    int li = (col0 == 0) ? 0 : col0 - 1;     // clamped left index
    int ri = (col0 == 60) ? 63 : col0 + 4;   // clamped right index

    for (int ip = 0; ip < 16; ++ip) {
        int plane = pbase + ip;
        int b = plane >> 9;
        int ch = plane & 511;

        // stage x plane into LDS (x is LLC-resident from phase 1; last use)
        const fx4* xp4 = (const fx4*)(x + (size_t)plane * 4096);
        fx4* t4 = (fx4*)tile;
#pragma unroll
        for (int k = 0; k < 4; ++k)
            t4[t + k * 256] = __builtin_nontemporal_load(xp4 + t + k * 256);

        // prefetch this thread's 4 s-rows now; HBM latency hides under the
        // scalar work + barrier + conv arithmetic below
        fx4 spre[4];
#pragma unroll
        for (int rr = 0; rr < 4; ++rr) {
            int row = ty + rr * 16;
            spre[rr] = __builtin_nontemporal_load(
                (const fx4*)(s + (size_t)plane * 4096 + row * 64 + col0));
        }

        // per-plane scalars (redundant per thread; broadcast loads)
        float q = 0.f, kk = 0.f;
#pragma unroll
        for (int i = 0; i < 5; ++i) {
            int cc = ch + i - 2;
            float yv = (cc >= 0 && cc < 512) ? y[b * 512 + cc] : 0.f;
            q += yv * wq[i];
            kk += yv * wk[i];
        }
        float qf = (q > 0.f) ? (q + 1.f) : expf(q);    // elu(q)+1
        float kf = (kk > 0.f) ? (kk + 1.f) : expf(kk); // elu(k)+1
        float zn = z[plane] + kf;
        if (t == 0) z_new[plane] = zn;
        float fac = qf * (1.0f / (qf * (zn + EPS)));   // matches ref op order

        const float* wvp = wv + ch * 9;
        float w00 = wvp[0], w01 = wvp[1], w02 = wvp[2];
        float w10 = wvp[3], w11 = wvp[4], w12 = wvp[5];
        float w20 = wvp[6], w21 = wvp[7], w22 = wvp[8];

        __syncthreads();   // tile staged

#pragma unroll
        for (int rr = 0; rr < 4; ++rr) {
            int row = ty + rr * 16;  // 0..63
            int rcB = row * 64;
            int rmB = (row == 0) ? rcB : rcB - 64;
            int rpB = (row == 63) ? rcB : rcB + 64;
            float tm = (row == 0) ? 0.f : 1.f;
            float bm = (row == 63) ? 0.f : 1.f;

            fx4 tq = *(const fx4*)(tile + rmB + col0);
            float t0 = tile[rmB + li] * (tm * lm);
            float t1 = tq.x * tm, t2 = tq.y * tm, t3 = tq.z * tm, t4v = tq.w * tm;
            float t5 = tile[rmB + ri] * (tm * rm);

            fx4 cq = *(const fx4*)(tile + rcB + col0);
            float c0 = tile[rcB + li] * lm;
            float c1 = cq.x, c2 = cq.y, c3 = cq.z, c4 = cq.w;
            float c5 = tile[rcB + ri] * rm;

            fx4 bq = *(const fx4*)(tile + rpB + col0);
            float b0 = tile[rpB + li] * (bm * lm);
            float b1 = bq.x * bm, b2 = bq.y * bm, b3 = bq.z * bm, b4 = bq.w * bm;
            float b5 = tile[rpB + ri] * (bm * rm);

            float v0 = t0 * w00 + t1 * w01 + t2 * w02 +
                       c0 * w10 + c1 * w11 + c2 * w12 +
                       b0 * w20 + b1 * w21 + b2 * w22;
            float v1 = t1 * w00 + t2 * w01 + t3 * w02 +
                       c1 * w10 + c2 * w11 + c3 * w12 +
                       b1 * w20 + b2 * w21 + b3 * w22;
            float v2 = t2 * w00 + t3 * w01 + t4v * w02 +
                       c2 * w10 + c3 * w11 + c4 * w12 +
                       b2 * w20 + b3 * w21 + b4 * w22;
            float v3 = t3 * w00 + t4v * w01 + t5 * w02 +
                       c3 * w10 + c4 * w11 + c5 * w12 +
                       b3 * w20 + b4 * w21 + b5 * w22;

            size_t off = (size_t)plane * 4096 + (size_t)rcB + col0;
            fx4 s4 = spre[rr];
            fx4 sn;
            sn.x = s4.x + kf * v0;
            sn.y = s4.y + kf * v1;
            sn.z = s4.z + kf * v2;
            sn.w = s4.w + kf * v3;
            __builtin_nontemporal_store(sn, (fx4*)(s_new + off));
            fx4 o;
            o.x = fac * sn.x;
            o.y = fac * sn.y;
            o.z = fac * sn.z;
            o.w = fac * sn.w;
            __builtin_nontemporal_store(o, (fx4*)(out + off));
        }
        __syncthreads();   // all tile reads done before next plane's staging
    }
}

extern "C" void kernel_launch(void* const* d_in, const int* in_sizes, int n_in,
                              void* d_out, int out_size, void* d_ws,
                              size_t ws_size, hipStream_t stream) {
    const float* x  = (const float*)d_in[0];  // [16,512,64,64]
    const float* s  = (const float*)d_in[1];  // [16,512,1,4096]
    const float* z  = (const float*)d_in[2];  // [16,1,512,1]
    const float* wq = (const float*)d_in[3];  // [1,1,5]
    const float* wk = (const float*)d_in[4];  // [1,1,5]
    const float* wv = (const float*)d_in[5];  // [512,1,3,3]

    float* out   = (float*)d_out;            // [16,512,64,64] = 33554432
    float* s_new = out + 33554432;           // [16,512,1,4096] = 33554432
    float* z_new = s_new + 33554432;         // [16,1,512,1] = 8192

    float* y = (float*)d_ws;                 // 8192 floats

    void* args[] = {(void*)&x, (void*)&s, (void*)&z, (void*)&wq, (void*)&wk,
                    (void*)&wv, (void*)&y, (void*)&out, (void*)&s_new,
                    (void*)&z_new};
    hipLaunchCooperativeKernel((const void*)mega_kernel, dim3(512), dim3(256),
                               args, 0, stream);
}

// Round 4
// 445.157 us; speedup vs baseline: 1.1678x; 1.1678x over previous
//
#include <hip/hip_runtime.h>
#include <math.h>

#define EPS 1e-6f

// Native clang vector type — required by __builtin_nontemporal_{load,store}
typedef float __attribute__((ext_vector_type(4))) fx4;

// ---------------- Kernel 1: per-(b,c) spatial mean of x (64x64 = 4096) -------
// Plain (caching) loads on purpose: this pass pulls x into L2/LLC so the
// fused kernel's re-read of x hits the 256 MB Infinity Cache instead of HBM.
__global__ __launch_bounds__(256) void mean_kernel(const float* __restrict__ x,
                                                   float* __restrict__ y) {
    int plane = blockIdx.x;  // b*512 + c, 8192 planes
    const fx4* xp = (const fx4*)(x + (size_t)plane * 4096);
    int t = threadIdx.x;
    float sum = 0.f;
#pragma unroll
    for (int k = 0; k < 4; ++k) {
        fx4 v = xp[t + k * 256];
        sum += v.x + v.y + v.z + v.w;
    }
    // wave64 shuffle reduce
#pragma unroll
    for (int off = 32; off > 0; off >>= 1)
        sum += __shfl_down(sum, off, 64);
    __shared__ float lds[4];
    if ((t & 63) == 0) lds[t >> 6] = sum;
    __syncthreads();
    if (t == 0) {
        float s = lds[0] + lds[1] + lds[2] + lds[3];
        y[plane] = s * (1.0f / 4096.0f);
    }
}

// ------- Kernel 2: fused qk + depthwise 3x3 conv + s_new + out ---------------
// One block per (b,c) plane. Halo columns come from wave shuffles (lane±1)
// instead of scalar LDS reads: the scalar reads were an 8-way bank conflict
// (all ty-rows alias bank-wise; li differs by 32 floats between tx and tx+8).
// The shuffle-invalid lanes (tx==0 left, tx==15 right) are exactly the ones
// masked to zero by lm/rm. s is prefetched into registers before the barrier
// so its HBM latency hides under the conv arithmetic.
__global__ __launch_bounds__(256) void fused_kernel(
    const float* __restrict__ x, const float* __restrict__ s,
    const float* __restrict__ z, const float* __restrict__ wq,
    const float* __restrict__ wk, const float* __restrict__ wv,
    const float* __restrict__ y, float* __restrict__ out,
    float* __restrict__ s_new, float* __restrict__ z_new) {
    __shared__ float tile[4096];

    int plane = blockIdx.x;      // b*512 + c
    int b = plane >> 9;
    int ch = plane & 511;
    int t = threadIdx.x;

    int ty = t >> 4;             // 0..15
    int tx = t & 15;             // 0..15
    int col0 = tx << 2;          // 0,4,...,60

    // ---- stage x plane into LDS (x is LLC-resident; last use) ----
    const fx4* xp4 = (const fx4*)(x + (size_t)plane * 4096);
    fx4* t4 = (fx4*)tile;
#pragma unroll
    for (int k = 0; k < 4; ++k)
        t4[t + k * 256] = __builtin_nontemporal_load(xp4 + t + k * 256);

    // ---- prefetch this thread's 4 s-rows (latency hides under the rest) ----
    fx4 spre[4];
#pragma unroll
    for (int rr = 0; rr < 4; ++rr) {
        int row = ty + rr * 16;
        spre[rr] = __builtin_nontemporal_load(
            (const fx4*)(s + (size_t)plane * 4096 + row * 64 + col0));
    }

    // ---- per-plane scalars (redundant per thread; broadcast loads) ----
    float q = 0.f, kk = 0.f;
#pragma unroll
    for (int i = 0; i < 5; ++i) {
        int cc = ch + i - 2;
        float yv = (cc >= 0 && cc < 512) ? y[b * 512 + cc] : 0.f;
        q += yv * wq[i];
        kk += yv * wk[i];
    }
    float qf = (q > 0.f) ? (q + 1.f) : expf(q);    // elu(q)+1
    float kf = (kk > 0.f) ? (kk + 1.f) : expf(kk); // elu(k)+1
    float zn = z[plane] + kf;
    if (t == 0) z_new[plane] = zn;
    float fac = qf * (1.0f / (qf * (zn + EPS)));   // matches ref op order

    const float* wvp = wv + ch * 9;
    float w00 = wvp[0], w01 = wvp[1], w02 = wvp[2];
    float w10 = wvp[3], w11 = wvp[4], w12 = wvp[5];
    float w20 = wvp[6], w21 = wvp[7], w22 = wvp[8];

    __syncthreads();

    // column-edge masks
    float lm = (col0 == 0) ? 0.f : 1.f;
    float rm = (col0 == 60) ? 0.f : 1.f;

#pragma unroll
    for (int rr = 0; rr < 4; ++rr) {
        int row = ty + rr * 16;  // 0..63
        int rcB = row * 64;
        int rmB = (row == 0) ? rcB : rcB - 64;
        int rpB = (row == 63) ? rcB : rcB + 64;
        float tm = (row == 0) ? 0.f : 1.f;
        float bm = (row == 63) ? 0.f : 1.f;

        fx4 tq = *(const fx4*)(tile + rmB + col0);
        fx4 cq = *(const fx4*)(tile + rcB + col0);
        fx4 bq = *(const fx4*)(tile + rpB + col0);

        // halo columns via lane shuffles; boundary lanes are masked by lm/rm
        float t0 = __shfl_up(tq.w, 1, 64) * (tm * lm);
        float t5 = __shfl_down(tq.x, 1, 64) * (tm * rm);
        float c0 = __shfl_up(cq.w, 1, 64) * lm;
        float c5 = __shfl_down(cq.x, 1, 64) * rm;
        float b0 = __shfl_up(bq.w, 1, 64) * (bm * lm);
        float b5 = __shfl_down(bq.x, 1, 64) * (bm * rm);

        float t1 = tq.x * tm, t2 = tq.y * tm, t3 = tq.z * tm, t4v = tq.w * tm;
        float c1 = cq.x, c2 = cq.y, c3 = cq.z, c4 = cq.w;
        float b1 = bq.x * bm, b2 = bq.y * bm, b3 = bq.z * bm, b4 = bq.w * bm;

        float v0 = t0 * w00 + t1 * w01 + t2 * w02 +
                   c0 * w10 + c1 * w11 + c2 * w12 +
                   b0 * w20 + b1 * w21 + b2 * w22;
        float v1 = t1 * w00 + t2 * w01 + t3 * w02 +
                   c1 * w10 + c2 * w11 + c3 * w12 +
                   b1 * w20 + b2 * w21 + b3 * w22;
        float v2 = t2 * w00 + t3 * w01 + t4v * w02 +
                   c2 * w10 + c3 * w11 + c4 * w12 +
                   b2 * w20 + b3 * w21 + b4 * w22;
        float v3 = t3 * w00 + t4v * w01 + t5 * w02 +
                   c3 * w10 + c4 * w11 + c5 * w12 +
                   b3 * w20 + b4 * w21 + b5 * w22;

        size_t off = (size_t)plane * 4096 + (size_t)rcB + col0;
        fx4 s4 = spre[rr];
        fx4 sn;
        sn.x = s4.x + kf * v0;
        sn.y = s4.y + kf * v1;
        sn.z = s4.z + kf * v2;
        sn.w = s4.w + kf * v3;
        __builtin_nontemporal_store(sn, (fx4*)(s_new + off));
        fx4 o;
        o.x = fac * sn.x;
        o.y = fac * sn.y;
        o.z = fac * sn.z;
        o.w = fac * sn.w;
        __builtin_nontemporal_store(o, (fx4*)(out + off));
    }
}

extern "C" void kernel_launch(void* const* d_in, const int* in_sizes, int n_in,
                              void* d_out, int out_size, void* d_ws,
                              size_t ws_size, hipStream_t stream) {
    const float* x  = (const float*)d_in[0];  // [16,512,64,64]
    const float* s  = (const float*)d_in[1];  // [16,512,1,4096]
    const float* z  = (const float*)d_in[2];  // [16,1,512,1]
    const float* wq = (const float*)d_in[3];  // [1,1,5]
    const float* wk = (const float*)d_in[4];  // [1,1,5]
    const float* wv = (const float*)d_in[5];  // [512,1,3,3]

    float* out   = (float*)d_out;            // [16,512,64,64] = 33554432
    float* s_new = out + 33554432;           // [16,512,1,4096] = 33554432
    float* z_new = s_new + 33554432;         // [16,1,512,1] = 8192

    float* y = (float*)d_ws;                 // 8192 floats

    mean_kernel<<<8192, 256, 0, stream>>>(x, y);
    fused_kernel<<<8192, 256, 0, stream>>>(x, s, z, wq, wk, wv, y,
                                           out, s_new, z_new);
}